// Round 9
// baseline (313.315 us; speedup 1.0000x reference)
//
#include <hip/hip_runtime.h>

#define T_LEN 256
#define D_IN 4
#define SPR 8                       // steps per x-prefetch round
#define NROUND 33                   // 264 steps >= T_LEN+2 (layer skew 0..2)

typedef __fp16 h8 __attribute__((ext_vector_type(8)));
typedef __fp16 cvt2_t __attribute__((ext_vector_type(2)));
typedef float float4v __attribute__((ext_vector_type(4)));

struct CellW { const float *Wih, *Whh, *bih, *bhh; };
struct Params { CellW c[6]; const float* y; float* hout; };

__device__ __forceinline__ float fexp2(float x) { return __builtin_amdgcn_exp2f(x); }
__device__ __forceinline__ float frcp(float x)  { return __builtin_amdgcn_rcpf(x); }
__device__ __forceinline__ int packh(float a, float b) {
    cvt2_t p = __builtin_amdgcn_cvt_pkrtz(a, b);
    return __builtin_bit_cast(int, p);
}
__device__ __forceinline__ h8 mk8(int a, int b, int c, int d) {
    int4 v; v.x = a; v.y = b; v.z = c; v.w = d;
    return __builtin_bit_cast(h8, v);
}

// K=32 MFMA, unit-gate-packed A with pi input-column permutation (R7-proven):
//   A row m -> (local unit m>>2, gate m&3); D lane(n,Q) reg r = gate r of
//   local unit Q, batch col n. MFMA j covers global units 8e+4j+Q.
//   pi: k-slot 4Q+i <-> input unit 4i+Q (Whh and Wih l>0), so the B operand's
//   unit-halves are exactly the writer-packed dwords (e0-pack, e1-pack).
#define MFMA32(a, b, c) __builtin_amdgcn_mfma_f32_16x16x32_f16(a, b, c, 0, 0, 0)

// Activation for 2 units (R6-8-proven, bitwise unchanged). p[0..3]=i,f,g,o
// pre-scaled by -log2e (i,f,o) / -2log2e (g), folded into A/bias. c-path
// common-denominator fusion, rcp paired across the 2 units: 10 exp2 + 2 rcp.
// Range audit (|pre| <= ~8): den<=2^47, pair<=2^94 < 2^128; Dh<=2^42
// (ec clamp 2^30), pair<2^84. No cancellation: err(c') ~ eps*max|fc|,|ig|.
__device__ __forceinline__ void act2(const float4v& pA, const float4v& pB,
                                     float& cA, float& cB,
                                     float& hA, float& hB) {
    float eiA = fexp2(pA[0]), efA = fexp2(pA[1]), egA = fexp2(pA[2]);
    float eiB = fexp2(pB[0]), efB = fexp2(pB[1]), egB = fexp2(pB[2]);
    float FA = 1.f + efA,              FB = 1.f + efB;
    float PA = (1.f + eiA) * (1.f + egA), PB = (1.f + eiB) * (1.f + egB);
    float NGA = 1.f - egA,             NGB = 1.f - egB;
    float denA = FA * PA,              denB = FB * PB;
    float numA = fmaf(cA, PA, NGA * FA);
    float numB = fmaf(cB, PB, NGB * FB);
    float RC = frcp(denA * denB);
    cA = numA * denB * RC;
    cB = numB * denA * RC;
    const float K2 = -2.8853900817779268f;     // -2*log2e
    float eoA = fexp2(pA[3]), ecA = fexp2(fminf(cA * K2, 30.f));
    float eoB = fexp2(pB[3]), ecB = fexp2(fminf(cB * K2, 30.f));
    float NOA = 1.f - ecA,    NOB = 1.f - ecB;
    float DhA = (1.f + eoA) * (1.f + ecA);
    float DhB = (1.f + eoB) * (1.f + ecB);
    float RH = frcp(DhA * DhB);
    hA = NOA * DhB * RH;
    hB = NOB * DhA * RH;
}

// R9: the unique 1024-wave uniform partition. Wave = (tile, dir, e-half),
// running ALL 3 layers in-wave with time skew (layer l does t = s - l at
// step s; layer l-1's step-(s-1) output is consumed from REGISTERS).
// Block = 4 waves (2 dir x 2 e) -> 1 wave/SIMD on every SIMD of the chip,
// identical work: no pace-SIMD (the flaw in R1-R8). Per step the wave has
// 3 independent act chains (in-wave ILP) to fill trans latency.
// Only remaining exchange: e-sibling packs, 3 b32 reads + 3 writes/step,
// conflict-free (R7 layout), parity double-buffered, 1 barrier/step.
// x: register prefetch in rounds of 8 (R1-proven), no x_lds.
// 96KB dynamic LDS pad caps the CU at 1 block -> exactly 4 waves/CU.
__global__ void __launch_bounds__(256)
lstm_wf_kernel(Params p)
{
    extern __shared__ int dyn_pad[];           // 96KB dynamic: 1 block/CU cap
    __shared__ int h_sl[2][2][2][3][4][16];    // [par][dir][e][l][Q][n] 6KB

    const int tid = threadIdx.x;
    const int v = tid >> 6;          // wave 0..3
    const int dir = v >> 1;
    const int e = v & 1;
    const int L = tid & 63;
    const int n = L & 15;            // batch col
    const int Q = L >> 4;

    const int b0 = blockIdx.x * 16;
    const float LOG2E = 1.4426950408889634f;

    if (p.y == nullptr) dyn_pad[0] = 1;        // keep dynamic pad allocated

    // ---- prepass: zero h slab (both parities) ----
    for (int i = tid; i < 2 * 2 * 2 * 3 * 4 * 16; i += 256)
        ((int*)h_sl)[i] = 0;

    // ---- A-frags + bias for all 3 layers of (dir) ----
    const int gate = n & 3;
    const int su = n >> 2;
    const float sA = (gate == 2) ? -2.f * LOG2E : -LOG2E;
    h8 A8[3][2];
    float4v bs[3][2];
#pragma unroll
    for (int l = 0; l < 3; ++l) {
        const CellW cw = p.c[dir * 3 + l];
#pragma unroll
        for (int j = 0; j < 2; ++j) {
            const int u = 8 * e + 4 * j + su;   // A-row unit
            const int row = gate * 16 + u;
            float vh[4], vp[4];
#pragma unroll
            for (int i = 0; i < 4; ++i) {
                const int col = 4 * i + Q;      // pi-permuted input unit
                vh[i] = cw.Whh[row * 16 + col];
                vp[i] = (l == 0) ? ((Q == 0) ? cw.Wih[row * D_IN + i] : 0.f)
                                 : cw.Wih[row * 16 + col];
            }
            A8[l][j] = mk8(packh(vh[0]*sA, vh[1]*sA), packh(vh[2]*sA, vh[3]*sA),
                           packh(vp[0]*sA, vp[1]*sA), packh(vp[2]*sA, vp[3]*sA));
            const int ub = 8 * e + 4 * j + Q;   // D reg r = gate r of unit ub
            const float br0 = cw.bih[0 * 16 + ub] + cw.bhh[0 * 16 + ub];
            const float br1 = cw.bih[1 * 16 + ub] + cw.bhh[1 * 16 + ub];
            const float br2 = cw.bih[2 * 16 + ub] + cw.bhh[2 * 16 + ub];
            const float br3 = cw.bih[3 * 16 + ub] + cw.bhh[3 * 16 + ub];
            bs[l][j] = (float4v){br0 * -LOG2E, br1 * -LOG2E,
                                 br2 * -2.f * LOG2E, br3 * -LOG2E};
        }
    }

    // ---- x prefetch prologue: round 0 (t = 0..7), Q==0 lanes (L<16) ----
    const float* ybase = p.y + (size_t)(b0 + n) * (T_LEN * D_IN);
    int2 xq[SPR], xn[SPR];
    if (L < 16) {
#pragma unroll
        for (int k = 0; k < SPR; ++k) {
            const int tt = dir ? (T_LEN - 1 - k) : k;
            const float4 xv = *(const float4*)(ybase + (size_t)tt * D_IN);
            xq[k].x = packh(xv.x, xv.y);
            xq[k].y = packh(xv.z, xv.w);
        }
    }

    __syncthreads();                 // prepass visible

    float c0[3] = {0.f, 0.f, 0.f};   // cell state, unit 8e+Q per layer
    float c1[3] = {0.f, 0.f, 0.f};   // cell state, unit 8e+4+Q per layer
    float h0[3] = {0.f, 0.f, 0.f};
    float h1[3] = {0.f, 0.f, 0.f};
    int own[3] = {0, 0, 0};          // own e-half packed h per layer

#pragma unroll 1
    for (int r = 0; r < NROUND; ++r) {
        // prefetch next round's x (consumed >= 8 steps later)
        if (L < 16) {
#pragma unroll
            for (int k = 0; k < SPR; ++k) {
                const int t = SPR * (r + 1) + k;
                if (t < T_LEN) {
                    const int tt = dir ? (T_LEN - 1 - t) : t;
                    const float4 xv = *(const float4*)(ybase + (size_t)tt * D_IN);
                    xn[k].x = packh(xv.x, xv.y);
                    xn[k].y = packh(xv.z, xv.w);
                }
            }
        }

#pragma unroll
        for (int k = 0; k < SPR; ++k) {
            const int s = SPR * r + k;
            const int pr = (s + 1) & 1;          // read parity (last step's)
            const int pw = s & 1;                // write parity
            // sibling packs (layer 0..2), conflict-free 2-way banked
            const int sib0 = h_sl[pr][dir][1 - e][0][Q][n];
            const int sib1 = h_sl[pr][dir][1 - e][1][Q][n];
            const int sib2 = h_sl[pr][dir][1 - e][2][Q][n];

            // ---- build B operands from OLD packs (snapshot), then MFMA ----
            // layer 0: prev-side = x packs (Q==0 lanes)
            const int x0 = (Q == 0) ? xq[k].x : 0;
            const int x1 = (Q == 0) ? xq[k].y : 0;
            const h8 b80 = mk8(e ? sib0 : own[0], e ? own[0] : sib0, x0, x1);
            const h8 b81 = mk8(e ? sib1 : own[1], e ? own[1] : sib1,
                               e ? sib0 : own[0], e ? own[0] : sib0);
            const h8 b82 = mk8(e ? sib2 : own[2], e ? own[2] : sib2,
                               e ? sib1 : own[1], e ? own[1] : sib1);

            const bool a0 = (s < T_LEN);
            const bool a1 = (s >= 1) && (s - 1 < T_LEN);
            const bool a2 = (s >= 2) && (s - 2 < T_LEN);

            float4v p00, p01, p10, p11, p20, p21;
            if (a0) { p00 = MFMA32(A8[0][0], b80, bs[0][0]);
                      p01 = MFMA32(A8[0][1], b80, bs[0][1]); }
            if (a1) { p10 = MFMA32(A8[1][0], b81, bs[1][0]);
                      p11 = MFMA32(A8[1][1], b81, bs[1][1]); }
            if (a2) { p20 = MFMA32(A8[2][0], b82, bs[2][0]);
                      p21 = MFMA32(A8[2][1], b82, bs[2][1]); }

            // ---- 3 independent act chains (in-wave ILP) ----
            if (a0) { act2(p00, p01, c0[0], c1[0], h0[0], h1[0]);
                      own[0] = packh(h0[0], h1[0]); }
            if (a1) { act2(p10, p11, c0[1], c1[1], h0[1], h1[1]);
                      own[1] = packh(h0[1], h1[1]); }
            if (a2) { act2(p20, p21, c0[2], c1[2], h0[2], h1[2]);
                      own[2] = packh(h0[2], h1[2]); }

            // publish own packs (stale for inactive layers: consumers guarded)
            h_sl[pw][dir][e][0][Q][n] = own[0];
            h_sl[pw][dir][e][1][Q][n] = own[1];
            h_sl[pw][dir][e][2][Q][n] = own[2];
            __syncthreads();
        }

        // roll x buffers (register copy; vmcnt wait lands here, a full
        // round after the loads were issued)
        if (L < 16) {
#pragma unroll
            for (int k = 0; k < SPR; ++k) xq[k] = xn[k];
        }
    }

    // final h3(T-1): units 8e+Q, 8e+4+Q of chain n
    float* o = p.hout + (size_t)(b0 + n) * 32 + dir * 16;
    o[8 * e + Q]     = h0[2];
    o[8 * e + 4 + Q] = h1[2];
}

__global__ void out_proj_kernel(const float* __restrict__ ws,
                                const float* __restrict__ Wout,
                                const float* __restrict__ bout,
                                float* __restrict__ out, int B)
{
    int idx = blockIdx.x * blockDim.x + threadIdx.x;
    if (idx >= B * 4) return;
    int b = idx >> 2, o = idx & 3;
    float acc = bout[o];
    const float* h = ws + (size_t)b * 32;
    const float* w = Wout + o * 32;
#pragma unroll
    for (int m = 0; m < 32; ++m) acc = fmaf(h[m], w[m], acc);
    out[idx] = acc;
}

extern "C" void kernel_launch(void* const* d_in, const int* in_sizes, int n_in,
                              void* d_out, int out_size, void* d_ws, size_t ws_size,
                              hipStream_t stream)
{
    const int B = in_sizes[0] / (T_LEN * D_IN); // 4096

    Params p;
    for (int s = 0; s < 6; ++s) {
        p.c[s].Wih = (const float*)d_in[1 + 4 * s];
        p.c[s].Whh = (const float*)d_in[2 + 4 * s];
        p.c[s].bih = (const float*)d_in[3 + 4 * s];
        p.c[s].bhh = (const float*)d_in[4 + 4 * s];
    }
    p.y = (const float*)d_in[0];
    p.hout = (float*)d_ws;

    const int blocks = B / 16;               // 1 tile (both dirs) per block
    lstm_wf_kernel<<<blocks, 256, 96 * 1024, stream>>>(p);

    const float* Wout = (const float*)d_in[25];
    const float* bout = (const float*)d_in[26];
    out_proj_kernel<<<(B * 4 + 255) / 256, 256, 0, stream>>>(
        (const float*)d_ws, Wout, bout, (float*)d_out, B);
}

// Round 10
// 230.380 us; speedup vs baseline: 1.3600x; 1.3600x over previous
//
#include <hip/hip_runtime.h>

#define T_LEN 256
#define D_IN 4

typedef __fp16 h8 __attribute__((ext_vector_type(8)));
typedef __fp16 cvt2_t __attribute__((ext_vector_type(2)));
typedef float float4v __attribute__((ext_vector_type(4)));

struct CellW { const float *Wih, *Whh, *bih, *bhh; };
struct Params { CellW c[6]; const float* y; float* hout; };

__device__ __forceinline__ float fexp2(float x) { return __builtin_amdgcn_exp2f(x); }
__device__ __forceinline__ float frcp(float x)  { return __builtin_amdgcn_rcpf(x); }
__device__ __forceinline__ int packh(float a, float b) {
    cvt2_t p = __builtin_amdgcn_cvt_pkrtz(a, b);
    return __builtin_bit_cast(int, p);
}
__device__ __forceinline__ h8 mk8(int a, int b, int c, int d) {
    int4 v; v.x = a; v.y = b; v.z = c; v.w = d;
    return __builtin_bit_cast(h8, v);
}

// K=32 MFMA, unit-gate-packed A with pi input-column permutation (R7/R8-proven):
//   A row m -> (local unit m>>2, gate m&3); D lane(n,Q) reg r = gate r of
//   local unit Q, batch col n. MFMA j covers global units 8e+4j+Q.
//   pi: k-slot 4Q+i <-> input unit 4i+Q (Whh and Wih l>0), so B elems 0-3 are
//   exactly the two writer-packed dwords (e0-pack, e1-pack); elems 4-7 are the
//   prev-layer packs (or x for l0). h exchange: 1 b32 write + <=3 b32 reads
//   per lane, 2-way banked (free; R8 measured 0 conflicts).
#define MFMA32(a, b, c) __builtin_amdgcn_mfma_f32_16x16x32_f16(a, b, c, 0, 0, 0)

// Activation for 2 units (R6-R8-proven, bitwise unchanged). p[0..3]=i,f,g,o
// pre-scaled by -log2e (i,f,o) / -2log2e (g), folded into A/bias. c-path
// common-denominator fusion, rcp paired across the 2 units: 10 exp2 + 2 rcp.
// Range audit (|pre| <= ~8): den<=2^47, pair<=2^94 < 2^128; Dh<=2^42
// (ec clamp 2^30), pair<2^84. No cancellation: err(c') ~ eps*max|fc|,|ig|.
__device__ __forceinline__ void act2(const float4v& pA, const float4v& pB,
                                     float& cA, float& cB,
                                     float& hA, float& hB) {
    float eiA = fexp2(pA[0]), efA = fexp2(pA[1]), egA = fexp2(pA[2]);
    float eiB = fexp2(pB[0]), efB = fexp2(pB[1]), egB = fexp2(pB[2]);
    float FA = 1.f + efA,              FB = 1.f + efB;
    float PA = (1.f + eiA) * (1.f + egA), PB = (1.f + eiB) * (1.f + egB);
    float NGA = 1.f - egA,             NGB = 1.f - egB;
    float denA = FA * PA,              denB = FB * PB;
    float numA = fmaf(cA, PA, NGA * FA);
    float numB = fmaf(cB, PB, NGB * FB);
    float RC = frcp(denA * denB);
    cA = numA * denB * RC;
    cB = numB * denA * RC;
    const float K2 = -2.8853900817779268f;     // -2*log2e
    float eoA = fexp2(pA[3]), ecA = fexp2(fminf(cA * K2, 30.f));
    float eoB = fexp2(pB[3]), ecB = fexp2(fminf(cB * K2, 30.f));
    float NOA = 1.f - ecA,    NOB = 1.f - ecB;
    float DhA = (1.f + eoA) * (1.f + ecA);
    float DhB = (1.f + eoB) * (1.f + ecB);
    float RH = frcp(DhA * DhB);
    hA = NOA * DhB * RH;
    hB = NOB * DhA * RH;
}

// R10 = R8's 12-wave block (2dir x 3layer x 2e; 3 waves/SIMD uniform barrier
// group -- the proven best partition) with a leaner step:
//  - own e-half pack kept in a REGISTER (R8 re-read it from LDS every step)
//  - x via 2-step-ahead register prefetch (no x_lds, no per-step x ds_read)
//  - branch-free main loop (guards hoisted to 2-step prologue/epilogue),
//    parities as literals in a 2-step-unrolled body (static indexing).
// Sync protocol bit-for-bit R8: parity double-buffer, 1 __syncthreads/step.
// LDS pad >80KB keeps 1 block/CU.
__global__ void __launch_bounds__(768)
__attribute__((amdgpu_waves_per_eu(3, 4)))
lstm_wf_kernel(Params p)
{
    __shared__ int h_sl[2][2][2][3][4][16];    // [par][dir][e][l][Q][n] 6KB
    __shared__ int pad_excl[19456];            // 76KB: forces 1 block/CU

    const int tid = threadIdx.x;
    const int v = tid >> 6;         // wave 0..11
    const int dir = (v >= 6);
    const int v6 = v - 6 * dir;
    const int l = v6 >> 1;          // layer 0..2
    const int e = v6 & 1;           // unit-half: units 8e..8e+7
    const int L = tid & 63;
    const int n = L & 15;           // batch col
    const int Q = L >> 4;

    const int b0 = blockIdx.x * 16;
    const CellW cw = p.c[dir * 3 + l];
    const float LOG2E = 1.4426950408889634f;

    if (tid == 767) pad_excl[0] = tid;         // keep pad alive

    // ---- prepass: zero h slab (both parities) ----
    for (int i = tid; i < 2 * 2 * 2 * 3 * 4 * 16; i += 768)
        ((int*)h_sl)[i] = 0;

    // ---- A-frags: row n -> (local unit n>>2, gate n&3); columns permuted
    // by pi (slot 4Q+i <-> input unit 4i+Q). Layer-0 x-columns natural. ----
    const int gate = n & 3;
    const int su = n >> 2;
    const float sA = (gate == 2) ? -2.f * LOG2E : -LOG2E;
    h8 A8[2];
    float4v bs[2];
#pragma unroll
    for (int j = 0; j < 2; ++j) {
        const int u = 8 * e + 4 * j + su;   // A-row unit
        const int row = gate * 16 + u;
        float vh[4], vp[4];
#pragma unroll
        for (int i = 0; i < 4; ++i) {
            const int col = 4 * i + Q;      // pi-permuted input unit
            vh[i] = cw.Whh[row * 16 + col];
            vp[i] = (l == 0) ? ((Q == 0) ? cw.Wih[row * D_IN + i] : 0.f)
                             : cw.Wih[row * 16 + col];
        }
        A8[j] = mk8(packh(vh[0] * sA, vh[1] * sA), packh(vh[2] * sA, vh[3] * sA),
                    packh(vp[0] * sA, vp[1] * sA), packh(vp[2] * sA, vp[3] * sA));
        const int ub = 8 * e + 4 * j + Q;   // D reg r = gate r of unit ub
        const float br0 = cw.bih[0 * 16 + ub] + cw.bhh[0 * 16 + ub];
        const float br1 = cw.bih[1 * 16 + ub] + cw.bhh[1 * 16 + ub];
        const float br2 = cw.bih[2 * 16 + ub] + cw.bhh[2 * 16 + ub];
        const float br3 = cw.bih[3 * 16 + ub] + cw.bhh[3 * 16 + ub];
        bs[j] = (float4v){br0 * -LOG2E, br1 * -LOG2E,
                          br2 * -2.f * LOG2E, br3 * -LOG2E};
    }

    // ---- x prologue: t=0 -> xr0, t=1 -> xr1 (l0 waves, lanes L<16) ----
    const float* ybase = p.y + (size_t)(b0 + n) * (T_LEN * D_IN);
    int2 xr0 = {0, 0}, xr1 = {0, 0};
    if (l == 0 && L < 16) {
        const int ta = dir ? (T_LEN - 1) : 0;
        const int tb = dir ? (T_LEN - 2) : 1;
        const float4 xa = *(const float4*)(ybase + (size_t)ta * D_IN);
        const float4 xb = *(const float4*)(ybase + (size_t)tb * D_IN);
        xr0.x = packh(xa.x, xa.y); xr0.y = packh(xa.z, xa.w);
        xr1.x = packh(xb.x, xb.y); xr1.y = packh(xb.z, xb.w);
    }

    __syncthreads();                 // prepass visible

    float cA = 0.f, cB = 0.f;        // cell state: units 8e+Q, 8e+4+Q
    float hA = 0.f, hB = 0.f;
    int ownpk = 0;                   // own e-half packed h (register copy)

    // One step: read sibling+prev packs, MFMA x2, act2, write own pack.
    // pr/pw passed as literals at every call site -> static parity.
    auto STEP = [&](int s, int pr, int pw, bool a0, bool a1, bool a2,
                    int2& xr) {
        const bool act = (l == 0) ? a0 : (l == 1) ? a1 : a2;  // wave-uniform
        if (act) {
            const int sib = h_sl[pr][dir][1 - e][l][Q][n];
            int pv0, pv1;
            if (l == 0) {
                pv0 = (Q == 0) ? xr.x : 0;
                pv1 = (Q == 0) ? xr.y : 0;
            } else {
                pv0 = h_sl[pr][dir][0][l - 1][Q][n];
                pv1 = h_sl[pr][dir][1][l - 1][Q][n];
            }
            const int pk0 = e ? sib : ownpk;
            const int pk1 = e ? ownpk : sib;
            const h8 b8 = mk8(pk0, pk1, pv0, pv1);
            float4v p0 = MFMA32(A8[0], b8, bs[0]);   // gates of unit 8e+Q
            float4v p1 = MFMA32(A8[1], b8, bs[1]);   // gates of unit 8e+4+Q
            act2(p0, p1, cA, cB, hA, hB);
            ownpk = packh(hA, hB);
            h_sl[pw][dir][e][l][Q][n] = ownpk;
            // x prefetch 2 steps ahead into the slot just consumed
            if (l == 0 && L < 16) {
                const int t2 = s + 2;
                if (t2 < T_LEN) {
                    const int tt = dir ? (T_LEN - 1 - t2) : t2;
                    const float4 xv = *(const float4*)(ybase + (size_t)tt * D_IN);
                    xr.x = packh(xv.x, xv.y);
                    xr.y = packh(xv.z, xv.w);
                }
            }
        }
        __syncthreads();
    };

    // prologue (guarded): s=0 (l0), s=1 (l0,l1)
    STEP(0, 1, 0, true, false, false, xr0);
    STEP(1, 0, 1, true, true, false, xr1);

    // main loop: s=2..255, all layers active, branch-free, 2-step unroll
#pragma unroll 1
    for (int s = 2; s < T_LEN; s += 2) {
        STEP(s,     1, 0, true, true, true, xr0);
        STEP(s + 1, 0, 1, true, true, true, xr1);
    }

    // epilogue (guarded): s=256 (l1,l2), s=257 (l2)
    STEP(256, 1, 0, false, true, true, xr0);
    STEP(257, 0, 1, false, false, true, xr1);

    // l2 waves hold h3(T-1): units 8e+Q, 8e+4+Q of chain n
    if (l == 2) {
        float* o = p.hout + (size_t)(b0 + n) * 32 + dir * 16;
        o[8 * e + Q]     = hA;
        o[8 * e + 4 + Q] = hB;
    }
}

__global__ void out_proj_kernel(const float* __restrict__ ws,
                                const float* __restrict__ Wout,
                                const float* __restrict__ bout,
                                float* __restrict__ out, int B)
{
    int idx = blockIdx.x * blockDim.x + threadIdx.x;
    if (idx >= B * 4) return;
    int b = idx >> 2, o = idx & 3;
    float acc = bout[o];
    const float* h = ws + (size_t)b * 32;
    const float* w = Wout + o * 32;
#pragma unroll
    for (int m = 0; m < 32; ++m) acc = fmaf(h[m], w[m], acc);
    out[idx] = acc;
}

extern "C" void kernel_launch(void* const* d_in, const int* in_sizes, int n_in,
                              void* d_out, int out_size, void* d_ws, size_t ws_size,
                              hipStream_t stream)
{
    const int B = in_sizes[0] / (T_LEN * D_IN); // 4096

    Params p;
    for (int s = 0; s < 6; ++s) {
        p.c[s].Wih = (const float*)d_in[1 + 4 * s];
        p.c[s].Whh = (const float*)d_in[2 + 4 * s];
        p.c[s].bih = (const float*)d_in[3 + 4 * s];
        p.c[s].bhh = (const float*)d_in[4 + 4 * s];
    }
    p.y = (const float*)d_in[0];
    p.hout = (float*)d_ws;

    const int blocks = B / 16;               // 16 chains + both dirs per block
    lstm_wf_kernel<<<blocks, 768, 0, stream>>>(p);

    const float* Wout = (const float*)d_in[25];
    const float* bout = (const float*)d_in[26];
    out_proj_kernel<<<(B * 4 + 255) / 256, 256, 0, stream>>>(
        (const float*)d_ws, Wout, bout, (float*)d_out, B);
}

// Round 11
// 220.873 us; speedup vs baseline: 1.4185x; 1.0430x over previous
//
#include <hip/hip_runtime.h>

#define T_LEN 256
#define D_IN 4

typedef __fp16 h8 __attribute__((ext_vector_type(8)));
typedef __fp16 cvt2_t __attribute__((ext_vector_type(2)));
typedef float float4v __attribute__((ext_vector_type(4)));

struct CellW { const float *Wih, *Whh, *bih, *bhh; };
struct Params {
    CellW c[6];
    const float* y;
    const float* Wout;
    const float* bout;
    float* out;
};

__device__ __forceinline__ float fexp2(float x) { return __builtin_amdgcn_exp2f(x); }
__device__ __forceinline__ float frcp(float x)  { return __builtin_amdgcn_rcpf(x); }
__device__ __forceinline__ int packh(float a, float b) {
    cvt2_t p = __builtin_amdgcn_cvt_pkrtz(a, b);
    return __builtin_bit_cast(int, p);
}
__device__ __forceinline__ h8 mk8(int a, int b, int c, int d) {
    int4 v; v.x = a; v.y = b; v.z = c; v.w = d;
    return __builtin_bit_cast(h8, v);
}

// K=32 MFMA, unit-gate-packed A with pi input-column permutation (R7-R10
// proven): A row m -> (local unit m>>2, gate m&3); D lane(n,Q) reg r = gate r
// of local unit Q, batch col n. MFMA j covers global units 8e+4j+Q.
// pi: k-slot 4Q+i <-> input unit 4i+Q. NEW (R11): the OWN-side (Whh) columns
// are additionally e-swapped (col = 4*((i+2e)&3)+Q) so that for BOTH e-halves
// the B operand is uniformly mk8(ownpk, sib, pv0, pv1) -- own pack always in
// dword0 -- removing the per-step e-cndmasks. Prev-side (Wih l>0) keeps
// natural pi (pv0 = e0-pack, pv1 = e1-pack, fixed). Exact reindex of the dot
// product -> bitwise identical results.
#define MFMA32(a, b, c) __builtin_amdgcn_mfma_f32_16x16x32_f16(a, b, c, 0, 0, 0)

// Activation for 2 units (R6-R10-proven, bitwise unchanged). p[0..3]=i,f,g,o
// pre-scaled by -log2e (i,f,o) / -2log2e (g), folded into A/bias. c-path
// common-denominator fusion, rcp paired across the 2 units: 10 exp2 + 2 rcp.
// Range audit (|pre| <= ~8): den<=2^47, pair<=2^94 < 2^128; Dh<=2^42
// (ec clamp 2^30), pair<2^84. No cancellation: err(c') ~ eps*max|fc|,|ig|.
__device__ __forceinline__ void act2(const float4v& pA, const float4v& pB,
                                     float& cA, float& cB,
                                     float& hA, float& hB) {
    float eiA = fexp2(pA[0]), efA = fexp2(pA[1]), egA = fexp2(pA[2]);
    float eiB = fexp2(pB[0]), efB = fexp2(pB[1]), egB = fexp2(pB[2]);
    float FA = 1.f + efA,              FB = 1.f + efB;
    float PA = (1.f + eiA) * (1.f + egA), PB = (1.f + eiB) * (1.f + egB);
    float NGA = 1.f - egA,             NGB = 1.f - egB;
    float denA = FA * PA,              denB = FB * PB;
    float numA = fmaf(cA, PA, NGA * FA);
    float numB = fmaf(cB, PB, NGB * FB);
    float RC = frcp(denA * denB);
    cA = numA * denB * RC;
    cB = numB * denA * RC;
    const float K2 = -2.8853900817779268f;     // -2*log2e
    float eoA = fexp2(pA[3]), ecA = fexp2(fminf(cA * K2, 30.f));
    float eoB = fexp2(pB[3]), ecB = fexp2(fminf(cB * K2, 30.f));
    float NOA = 1.f - ecA,    NOB = 1.f - ecB;
    float DhA = (1.f + eoA) * (1.f + ecA);
    float DhB = (1.f + eoB) * (1.f + ecB);
    float RH = frcp(DhA * DhB);
    hA = NOA * DhB * RH;
    hB = NOB * DhA * RH;
}

// R11 = R10's 12-wave block (2dir x 3layer x 2e; 3 waves/SIMD uniform -- the
// unique optimal partition, see R10 ledger) with a leaner step:
//  - e-uniform B operand (A-frag e-swap): no per-step e-cndmasks
//  - xr selects removed (Q!=0 lanes' xr provably zero)
//  - slab [par][dir][l][e][Q][n]: prev-layer pack pair 256B apart
//    (ds_read2st64 merge candidate); banks unchanged (2-way, free)
//  - out_proj FUSED: l2 waves dump f32 h3 to LDS, 64 lanes finish the
//    16x4 projection (kills the second launch; f32 path, absmax unchanged)
// Sync protocol bit-for-bit R8/R10: parity double-buffer, 1 barrier/step.
__global__ void __launch_bounds__(768)
__attribute__((amdgpu_waves_per_eu(3, 4)))
lstm_wf_kernel(Params p)
{
    __shared__ int h_sl[2][2][3][2][4][16];    // [par][dir][l][e][Q][n] 6KB
    __shared__ float hf[16][33];               // f32 h3 staging, +1 pad

    const int tid = threadIdx.x;
    const int v = tid >> 6;         // wave 0..11
    const int dir = (v >= 6);
    const int v6 = v - 6 * dir;
    const int l = v6 >> 1;          // layer 0..2
    const int e = v6 & 1;           // unit-half: units 8e..8e+7
    const int L = tid & 63;
    const int n = L & 15;           // batch col
    const int Q = L >> 4;

    const int b0 = blockIdx.x * 16;
    const CellW cw = p.c[dir * 3 + l];
    const float LOG2E = 1.4426950408889634f;

    // ---- prepass: zero h slab (both parities) ----
    for (int i = tid; i < 2 * 2 * 3 * 2 * 4 * 16; i += 768)
        ((int*)h_sl)[i] = 0;

    // ---- A-frags: row n -> (local unit n>>2, gate n&3). Own-side columns
    // pi + e-swap; prev-side columns natural pi. ----
    const int gate = n & 3;
    const int su = n >> 2;
    const float sA = (gate == 2) ? -2.f * LOG2E : -LOG2E;
    h8 A8[2];
    float4v bs[2];
#pragma unroll
    for (int j = 0; j < 2; ++j) {
        const int u = 8 * e + 4 * j + su;   // A-row unit
        const int row = gate * 16 + u;
        float vh[4], vp[4];
#pragma unroll
        for (int i = 0; i < 4; ++i) {
            const int colh = 4 * ((i + 2 * e) & 3) + Q;  // own-side, e-swapped
            vh[i] = cw.Whh[row * 16 + colh];
            vp[i] = (l == 0) ? ((Q == 0) ? cw.Wih[row * D_IN + i] : 0.f)
                             : cw.Wih[row * 16 + 4 * i + Q];  // prev, natural
        }
        A8[j] = mk8(packh(vh[0] * sA, vh[1] * sA), packh(vh[2] * sA, vh[3] * sA),
                    packh(vp[0] * sA, vp[1] * sA), packh(vp[2] * sA, vp[3] * sA));
        const int ub = 8 * e + 4 * j + Q;   // D reg r = gate r of unit ub
        const float br0 = cw.bih[0 * 16 + ub] + cw.bhh[0 * 16 + ub];
        const float br1 = cw.bih[1 * 16 + ub] + cw.bhh[1 * 16 + ub];
        const float br2 = cw.bih[2 * 16 + ub] + cw.bhh[2 * 16 + ub];
        const float br3 = cw.bih[3 * 16 + ub] + cw.bhh[3 * 16 + ub];
        bs[j] = (float4v){br0 * -LOG2E, br1 * -LOG2E,
                          br2 * -2.f * LOG2E, br3 * -LOG2E};
    }

    // ---- x prologue: t=0 -> xr0, t=1 -> xr1 (l0 waves, lanes L<16).
    // L>=16 lanes keep xr == {0,0} forever -> no per-step masking needed. ----
    const float* ybase = p.y + (size_t)(b0 + n) * (T_LEN * D_IN);
    int2 xr0 = {0, 0}, xr1 = {0, 0};
    if (l == 0 && L < 16) {
        const int ta = dir ? (T_LEN - 1) : 0;
        const int tb = dir ? (T_LEN - 2) : 1;
        const float4 xa = *(const float4*)(ybase + (size_t)ta * D_IN);
        const float4 xb = *(const float4*)(ybase + (size_t)tb * D_IN);
        xr0.x = packh(xa.x, xa.y); xr0.y = packh(xa.z, xa.w);
        xr1.x = packh(xb.x, xb.y); xr1.y = packh(xb.z, xb.w);
    }

    __syncthreads();                 // prepass visible

    float cA = 0.f, cB = 0.f;        // cell state: units 8e+Q, 8e+4+Q
    float hA = 0.f, hB = 0.f;
    int ownpk = 0;                   // own e-half packed h (register)

    // One step. pr/pw literals at every call site -> static parity.
    auto STEP = [&](int s, int pr, int pw, bool a0, bool a1, bool a2,
                    int2& xr) {
        const bool act = (l == 0) ? a0 : (l == 1) ? a1 : a2;  // wave-uniform
        if (act) {
            const int sib = h_sl[pr][dir][l][1 - e][Q][n];
            int pv0, pv1;
            if (l == 0) {
                pv0 = xr.x;                     // zero in Q!=0 lanes by constr.
                pv1 = xr.y;
            } else {
                pv0 = h_sl[pr][dir][l - 1][0][Q][n];   // 256B apart ->
                pv1 = h_sl[pr][dir][l - 1][1][Q][n];   // read2st64 candidate
            }
            const h8 b8 = mk8(ownpk, sib, pv0, pv1);   // uniform for both e
            float4v p0 = MFMA32(A8[0], b8, bs[0]);     // gates of unit 8e+Q
            float4v p1 = MFMA32(A8[1], b8, bs[1]);     // gates of unit 8e+4+Q
            act2(p0, p1, cA, cB, hA, hB);
            ownpk = packh(hA, hB);
            h_sl[pw][dir][l][e][Q][n] = ownpk;
            // x prefetch 2 steps ahead into the slot just consumed
            if (l == 0 && L < 16) {
                const int t2 = s + 2;
                if (t2 < T_LEN) {
                    const int tt = dir ? (T_LEN - 1 - t2) : t2;
                    const float4 xv = *(const float4*)(ybase + (size_t)tt * D_IN);
                    xr.x = packh(xv.x, xv.y);
                    xr.y = packh(xv.z, xv.w);
                }
            }
        }
        __syncthreads();
    };

    // prologue (guarded): s=0 (l0), s=1 (l0,l1)
    STEP(0, 1, 0, true, false, false, xr0);
    STEP(1, 0, 1, true, true, false, xr1);

    // main loop: s=2..255, all layers active, branch-free, 2-step unroll
#pragma unroll 1
    for (int s = 2; s < T_LEN; s += 2) {
        STEP(s,     1, 0, true, true, true, xr0);
        STEP(s + 1, 0, 1, true, true, true, xr1);
    }

    // epilogue (guarded): s=256 (l1,l2), s=257 (l2)
    STEP(256, 1, 0, false, true, true, xr0);
    STEP(257, 0, 1, false, false, true, xr1);

    // ---- fused out_proj ----
    // l2 waves stage f32 h3 (units 8e+Q, 8e+4+Q of chain n, per dir)
    if (l == 2) {
        hf[n][dir * 16 + 8 * e + Q]     = hA;
        hf[n][dir * 16 + 8 * e + 4 + Q] = hB;
    }
    __syncthreads();
    if (tid < 64) {
        const int cn = tid >> 2, o = tid & 3;
        float acc = p.bout[o];
        const float* w = p.Wout + o * 32;
#pragma unroll
        for (int m = 0; m < 32; ++m) acc = fmaf(hf[cn][m], w[m], acc);
        p.out[(size_t)(b0 + cn) * 4 + o] = acc;
    }
}

extern "C" void kernel_launch(void* const* d_in, const int* in_sizes, int n_in,
                              void* d_out, int out_size, void* d_ws, size_t ws_size,
                              hipStream_t stream)
{
    const int B = in_sizes[0] / (T_LEN * D_IN); // 4096

    Params p;
    for (int s = 0; s < 6; ++s) {
        p.c[s].Wih = (const float*)d_in[1 + 4 * s];
        p.c[s].Whh = (const float*)d_in[2 + 4 * s];
        p.c[s].bih = (const float*)d_in[3 + 4 * s];
        p.c[s].bhh = (const float*)d_in[4 + 4 * s];
    }
    p.y = (const float*)d_in[0];
    p.Wout = (const float*)d_in[25];
    p.bout = (const float*)d_in[26];
    p.out = (float*)d_out;

    const int blocks = B / 16;               // 16 chains + both dirs per block
    lstm_wf_kernel<<<blocks, 768, 0, stream>>>(p);
}